// Round 11
// baseline (360.541 us; speedup 1.0000x reference)
//
#include <hip/hip_runtime.h>
#include <hip/hip_bf16.h>
#include <hip/hip_fp16.h>

typedef _Float16 f16x8 __attribute__((ext_vector_type(8)));
typedef _Float16 f16x4v __attribute__((ext_vector_type(4)));
typedef float f32x4 __attribute__((ext_vector_type(4)));

#define N_PTS 32768
#define NCHUNK 65       // 64 h-chunks + 1 bias chunk (h == 1)
#define ROWS 64         // rows per block
#define H_STRIDE 72     // f16; 144 B rows: 16B-aligned b128, reads 2-way max
#define X_STRIDE 72
#define P_STRIDE 68

// ---- prep: repack W2 + b2 into f16 MFMA fragment layout (proven R6 version)
__global__ __launch_bounds__(256) void prep_kernel(
    const float* __restrict__ W2, const float* __restrict__ b2,
    _Float16* __restrict__ wsB) {
  __shared__ _Float16 w_lds[64][X_STRIDE];
  const int c   = blockIdx.x;
  const int tid = threadIdx.x;
  {
    const float* src = (c < 64) ? (W2 + c * 4096 + tid * 16) : (b2 + tid * 16);
    int kl = tid >> 2, o = (tid & 3) * 16;
    f16x8 v0, v1;
    #pragma unroll
    for (int j = 0; j < 8; ++j) {
      v0[j] = (_Float16)src[j];
      v1[j] = (_Float16)src[8 + j];
    }
    *(f16x8*)(&w_lds[kl][o])     = v0;
    *(f16x8*)(&w_lds[kl][o + 8]) = v1;
  }
  __syncthreads();
  #pragma unroll
  for (int u = 0; u < 2; ++u) {
    int t = tid + u * 256;
    int q = t >> 6, lane = t & 63;
    int klbase = (q >> 2) * 32 + ((lane >> 4) & 3) * 8;
    int o      = (q & 3) * 16 + (lane & 15);
    f16x8 v;
    #pragma unroll
    for (int j = 0; j < 8; ++j) v[j] = w_lds[klbase + j][o];
    *(f16x8*)(wsB + c * 4096 + t * 8) = v;
  }
}

// ======== ABLATION A: staging stream only (R7 K-loop loads, no compute) ====
// REP=8. Loads kept alive via asm "+v" (zero instructions); per-rep memory
// clobber blocks cross-rep CSE. Sink write to d_out (main overwrites later).
__global__ __launch_bounds__(256) void abl_stage(
    const _Float16* __restrict__ wsB, float* __restrict__ sink) {
  const int tid  = threadIdx.x;
  const int lane = tid & 63;
  const int wave = tid >> 6;
  const _Float16* bp = wsB + lane * 8;

  f16x8 bA[8], bB[8], bC[8];
  auto LOADB = [&](f16x8* b, int c) {
    #pragma unroll
    for (int q = 0; q < 8; ++q)
      b[q] = *(const f16x8*)(bp + (c * 8 + q) * 512);
  };
  auto CONSUME = [&](f16x8* b) {
    #pragma unroll
    for (int q = 0; q < 8; ++q)
      asm volatile("" : "+v"(b[q]));
  };

  #pragma unroll 1
  for (int rep = 0; rep < 8; ++rep) {
    asm volatile("" ::: "memory");
    LOADB(bA, wave); LOADB(bB, wave + 4); LOADB(bC, wave + 8);
    #pragma unroll
    for (int g = 0; g < 5; ++g) {
      CONSUME(bA);
      if (3 * g + 3 < 16) LOADB(bA, wave + 4 * (3 * g + 3));
      CONSUME(bB);
      if (3 * g + 4 < 16) LOADB(bB, wave + 4 * (3 * g + 4));
      CONSUME(bC);
      if (3 * g + 5 < 16) LOADB(bC, wave + 4 * (3 * g + 5));
    }
    CONSUME(bA);
  }
  sink[blockIdx.x * 256 + tid] = (float)lane;
}

// ======== ABLATION B: compute only (R7 COMPUTE + rolling LOADH, B static) ==
// REP=24. B-frags loaded once; h phase + xf identical to main; acc -> sink.
__global__ __launch_bounds__(256) void abl_mma(
    const float* __restrict__ x, const float* __restrict__ gridp,
    const float* __restrict__ W1, const float* __restrict__ b1,
    const _Float16* __restrict__ wsB, float* __restrict__ sink) {
  __shared__ _Float16 h_lds[ROWS][H_STRIDE];

  const int tid  = threadIdx.x;
  const int lane = tid & 63;
  const int wave = tid >> 6;
  const int rowblk = blockIdx.x * ROWS;
  const int mrow = lane & 15;
  const int kgrp = lane >> 4;

  {
    int row = tid >> 2;
    int kb  = (tid & 3) * 16;
    int r = rowblk + row;
    float g0 = gridp[r * 3 + 0], g1 = gridp[r * 3 + 1], g2 = gridp[r * 3 + 2];
    f16x8 h0, h1;
    #pragma unroll
    for (int q = 0; q < 16; ++q) {
      int k = kb + q;
      float v = g0 * W1[k] + g1 * W1[64 + k] + g2 * W1[128 + k] + b1[k];
      float h = 0.5f * v * (1.0f + erff(v * 0.7071067811865476f));
      if (q < 8) h0[q] = (_Float16)h; else h1[q - 8] = (_Float16)h;
    }
    *(f16x8*)(&h_lds[row][kb])     = h0;
    *(f16x8*)(&h_lds[row][kb + 8]) = h1;
  }
  __syncthreads();

  f16x8 xf[4][2];
  #pragma unroll
  for (int m = 0; m < 4; ++m)
    #pragma unroll
    for (int s = 0; s < 2; ++s) {
      const float* xp = x + (rowblk + m * 16 + mrow) * 64 + s * 32 + kgrp * 8;
      f32x4 a = *(const f32x4*)(xp);
      f32x4 b = *(const f32x4*)(xp + 4);
      f16x8 v;
      #pragma unroll
      for (int j = 0; j < 4; ++j) { v[j] = (_Float16)a[j]; v[4 + j] = (_Float16)b[j]; }
      xf[m][s] = v;
    }

  const _Float16* bp = wsB + lane * 8;
  f16x8 bA[8], bB[8], bC[8];
  #pragma unroll
  for (int q = 0; q < 8; ++q) {
    bA[q] = *(const f16x8*)(bp + ((wave)     * 8 + q) * 512);
    bB[q] = *(const f16x8*)(bp + ((wave + 4) * 8 + q) * 512);
    bC[q] = *(const f16x8*)(bp + ((wave + 8) * 8 + q) * 512);
  }

  f32x4 acc[4][4];
  #pragma unroll
  for (int m = 0; m < 4; ++m)
    #pragma unroll
    for (int n = 0; n < 4; ++n)
      acc[m][n] = (f32x4){0.f, 0.f, 0.f, 0.f};

  auto LOADH = [&](int c) -> f16x4v {
    f16x4v h;
    #pragma unroll
    for (int m = 0; m < 4; ++m) h[m] = h_lds[m * 16 + mrow][c];
    return h;
  };
  auto COMPUTE = [&](const f16x8* b, f16x4v hv) {
    #pragma unroll
    for (int m = 0; m < 4; ++m) {
      _Float16 hh = hv[m];
      f16x8 hs = {hh, hh, hh, hh, hh, hh, hh, hh};
      f16x8 a0 = xf[m][0] * hs;
      f16x8 a1 = xf[m][1] * hs;
      #pragma unroll
      for (int n = 0; n < 4; ++n) {
        acc[m][n] = __builtin_amdgcn_mfma_f32_16x16x32_f16(a0, b[n],     acc[m][n], 0, 0, 0);
        acc[m][n] = __builtin_amdgcn_mfma_f32_16x16x32_f16(a1, b[4 + n], acc[m][n], 0, 0, 0);
      }
    }
  };

  f16x4v ha, hb, hc;
  #pragma unroll 1
  for (int rep = 0; rep < 24; ++rep) {
    asm volatile("" ::: "memory");
    ha = LOADH(wave); hb = LOADH(wave + 4); hc = LOADH(wave + 8);
    #pragma unroll
    for (int g = 0; g < 5; ++g) {
      COMPUTE(bA, ha);
      if (3 * g + 3 < 16) ha = LOADH(wave + 4 * (3 * g + 3));
      COMPUTE(bB, hb);
      if (3 * g + 4 < 16) hb = LOADH(wave + 4 * (3 * g + 4));
      COMPUTE(bC, hc);
      if (3 * g + 5 < 16) hc = LOADH(wave + 4 * (3 * g + 5));
    }
    COMPUTE(bA, ha);
  }

  // sink: 16 floats per thread, races-free, fully overwritten by main later
  int idx = blockIdx.x * 256 + tid;
  #pragma unroll
  for (int m = 0; m < 4; ++m)
    *(f32x4*)(sink + idx * 16 + m * 4) = acc[m][0] + acc[m][1] + acc[m][2] + acc[m][3];
}

// ---- main fused kernel: EXACT R7 best (31.9 us total) ----
__global__ __launch_bounds__(256) void main_kernel(
    const float* __restrict__ x, const float* __restrict__ gridp,
    const float* __restrict__ W1, const float* __restrict__ b1,
    const _Float16* __restrict__ wsB, float* __restrict__ out) {

  __shared__ _Float16 h_lds[ROWS][H_STRIDE];
  __shared__ float part[4][ROWS * P_STRIDE];
  _Float16* x_lds = (_Float16*)&part[0][0];

  const int tid  = threadIdx.x;
  const int lane = tid & 63;
  const int wave = tid >> 6;
  const int rowblk = blockIdx.x * ROWS;

  const float* xsrc = x + rowblk * 64 + tid * 16;
  f32x4 xr0 = *(const f32x4*)(xsrc);
  f32x4 xr1 = *(const f32x4*)(xsrc + 4);
  f32x4 xr2 = *(const f32x4*)(xsrc + 8);
  f32x4 xr3 = *(const f32x4*)(xsrc + 12);

  {
    int row = tid >> 2;
    int kb  = (tid & 3) * 16;
    int r = rowblk + row;
    float g0 = gridp[r * 3 + 0], g1 = gridp[r * 3 + 1], g2 = gridp[r * 3 + 2];
    f16x8 h0, h1;
    #pragma unroll
    for (int q = 0; q < 16; ++q) {
      int k = kb + q;
      float v = g0 * W1[k] + g1 * W1[64 + k] + g2 * W1[128 + k] + b1[k];
      float h = 0.5f * v * (1.0f + erff(v * 0.7071067811865476f));
      if (q < 8) h0[q] = (_Float16)h; else h1[q - 8] = (_Float16)h;
    }
    *(f16x8*)(&h_lds[row][kb])     = h0;
    *(f16x8*)(&h_lds[row][kb + 8]) = h1;
  }

  {
    int row = tid >> 2, o = (tid & 3) * 16;
    f16x8 v0, v1;
    #pragma unroll
    for (int j = 0; j < 4; ++j) {
      v0[j]     = (_Float16)xr0[j];
      v0[4 + j] = (_Float16)xr1[j];
      v1[j]     = (_Float16)xr2[j];
      v1[4 + j] = (_Float16)xr3[j];
    }
    *(f16x8*)(&x_lds[row * X_STRIDE + o])     = v0;
    *(f16x8*)(&x_lds[row * X_STRIDE + o + 8]) = v1;
  }
  __syncthreads();

  const int mrow = lane & 15;
  const int kgrp = lane >> 4;
  const _Float16* bp = wsB + lane * 8;

  auto LOADB = [&](f16x8* b, int c) {
    #pragma unroll
    for (int q = 0; q < 8; ++q)
      b[q] = *(const f16x8*)(bp + (c * 8 + q) * 512);
  };
  auto LOADH = [&](int c) -> f16x4v {
    f16x4v h;
    #pragma unroll
    for (int m = 0; m < 4; ++m) h[m] = h_lds[m * 16 + mrow][c];
    return h;
  };

  f16x8 bA[8], bB[8], bC[8];
  f16x4v ha, hb, hc;
  LOADB(bA, wave);      ha = LOADH(wave);
  LOADB(bB, wave + 4);  hb = LOADH(wave + 4);
  LOADB(bC, wave + 8);  hc = LOADH(wave + 8);

  f16x8 xf[4][2];
  #pragma unroll
  for (int m = 0; m < 4; ++m)
    #pragma unroll
    for (int s = 0; s < 2; ++s)
      xf[m][s] = *(const f16x8*)(&x_lds[(m * 16 + mrow) * X_STRIDE + s * 32 + kgrp * 8]);

  f32x4 acc[4][4];
  #pragma unroll
  for (int m = 0; m < 4; ++m)
    #pragma unroll
    for (int n = 0; n < 4; ++n)
      acc[m][n] = (f32x4){0.f, 0.f, 0.f, 0.f};

  auto COMPUTE = [&](const f16x8* b, f16x4v hv) {
    #pragma unroll
    for (int m = 0; m < 4; ++m) {
      _Float16 hh = hv[m];
      f16x8 hs = {hh, hh, hh, hh, hh, hh, hh, hh};
      f16x8 a0 = xf[m][0] * hs;
      f16x8 a1 = xf[m][1] * hs;
      #pragma unroll
      for (int n = 0; n < 4; ++n) {
        acc[m][n] = __builtin_amdgcn_mfma_f32_16x16x32_f16(a0, b[n],     acc[m][n], 0, 0, 0);
        acc[m][n] = __builtin_amdgcn_mfma_f32_16x16x32_f16(a1, b[4 + n], acc[m][n], 0, 0, 0);
      }
    }
  };
  auto COMPUTE_BIAS = [&](const f16x8* b) {
    #pragma unroll
    for (int m = 0; m < 4; ++m)
      #pragma unroll
      for (int n = 0; n < 4; ++n) {
        acc[m][n] = __builtin_amdgcn_mfma_f32_16x16x32_f16(xf[m][0], b[n],     acc[m][n], 0, 0, 0);
        acc[m][n] = __builtin_amdgcn_mfma_f32_16x16x32_f16(xf[m][1], b[4 + n], acc[m][n], 0, 0, 0);
      }
  };

  #pragma unroll
  for (int g = 0; g < 5; ++g) {
    COMPUTE(bA, ha);
    if (3 * g + 3 < 16) { LOADB(bA, wave + 4 * (3 * g + 3)); ha = LOADH(wave + 4 * (3 * g + 3)); }
    COMPUTE(bB, hb);
    if (3 * g + 4 < 16) { LOADB(bB, wave + 4 * (3 * g + 4)); hb = LOADH(wave + 4 * (3 * g + 4)); }
    else if (wave == 0) { LOADB(bB, 64); }
    COMPUTE(bC, hc);
    if (3 * g + 5 < 16) { LOADB(bC, wave + 4 * (3 * g + 5)); hc = LOADH(wave + 4 * (3 * g + 5)); }
  }
  COMPUTE(bA, ha);
  if (wave == 0) COMPUTE_BIAS(bB);

  __syncthreads();

  {
    float* pw = part[wave];
    #pragma unroll
    for (int m = 0; m < 4; ++m)
      #pragma unroll
      for (int n = 0; n < 4; ++n)
        #pragma unroll
        for (int r = 0; r < 4; ++r)
          pw[(m * 16 + kgrp * 4 + r) * P_STRIDE + n * 16 + mrow] = acc[m][n][r];
  }
  __syncthreads();

  {
    int row = tid >> 2;
    int cb  = (tid & 3) * 16;
    const float* p0 = part[0] + row * P_STRIDE + cb;
    float* op = out + (rowblk + row) * 64 + cb;
    #pragma unroll
    for (int j = 0; j < 4; ++j) {
      f32x4 s = *(const f32x4*)(p0 + j * 4);
      #pragma unroll
      for (int w = 1; w < 4; ++w)
        s += *(const f32x4*)(p0 + w * (ROWS * P_STRIDE) + j * 4);
      *(f32x4*)(op + j * 4) = s;
    }
  }
}

extern "C" void kernel_launch(void* const* d_in, const int* in_sizes, int n_in,
                              void* d_out, int out_size, void* d_ws, size_t ws_size,
                              hipStream_t stream) {
  const float* x    = (const float*)d_in[0];
  const float* grid = (const float*)d_in[1];
  const float* W1   = (const float*)d_in[2];
  const float* b1   = (const float*)d_in[3];
  const float* W2   = (const float*)d_in[4];
  const float* b2   = (const float*)d_in[5];
  float* out = (float*)d_out;
  _Float16* wsB = (_Float16*)d_ws;   // 65*4096*2 = 532480 bytes

  hipLaunchKernelGGL(prep_kernel, dim3(NCHUNK), dim3(256), 0, stream,
                     W2, b2, wsB);
  // --- measurement-round ablations (sink = d_out; main overwrites below) ---
  hipLaunchKernelGGL(abl_stage, dim3(N_PTS / ROWS), dim3(256), 0, stream,
                     wsB, out);
  hipLaunchKernelGGL(abl_mma, dim3(N_PTS / ROWS), dim3(256), 0, stream,
                     x, grid, W1, b1, wsB, out);
  // --- real kernel (R7 baseline), runs last, fully rewrites d_out ---
  hipLaunchKernelGGL(main_kernel, dim3(N_PTS / ROWS), dim3(256), 0, stream,
                     x, grid, W1, b1, wsB, out);
}

// Round 12
// 30.327 us; speedup vs baseline: 11.8886x; 11.8886x over previous
//
#include <hip/hip_runtime.h>
#include <hip/hip_bf16.h>
#include <hip/hip_fp16.h>

typedef _Float16 f16x8 __attribute__((ext_vector_type(8)));
typedef float f32x4 __attribute__((ext_vector_type(4)));

#define N_PTS 32768
#define NCHUNK 65       // 64 h-chunks + 1 bias chunk (h == 1)
#define ROWS 64         // rows per block
#define X_STRIDE 72     // f16; 144 B rows: 16B-aligned b128, reads 2-way max
#define P_STRIDE 68     // f32; 272 B rows: 16B-aligned

// ---- prep: repack W2 + b2 into f16 MFMA fragment layout (proven R6 version)
__global__ __launch_bounds__(256) void prep_kernel(
    const float* __restrict__ W2, const float* __restrict__ b2,
    _Float16* __restrict__ wsB) {
  __shared__ _Float16 w_lds[64][X_STRIDE];
  const int c   = blockIdx.x;
  const int tid = threadIdx.x;
  {
    const float* src = (c < 64) ? (W2 + c * 4096 + tid * 16) : (b2 + tid * 16);
    int kl = tid >> 2, o = (tid & 3) * 16;
    f16x8 v0, v1;
    #pragma unroll
    for (int j = 0; j < 8; ++j) {
      v0[j] = (_Float16)src[j];
      v1[j] = (_Float16)src[8 + j];
    }
    *(f16x8*)(&w_lds[kl][o])     = v0;
    *(f16x8*)(&w_lds[kl][o + 8]) = v1;
  }
  __syncthreads();
  #pragma unroll
  for (int u = 0; u < 2; ++u) {
    int t = tid + u * 256;
    int q = t >> 6, lane = t & 63;
    int klbase = (q >> 2) * 32 + ((lane >> 4) & 3) * 8;
    int o      = (q & 3) * 16 + (lane & 15);
    f16x8 v;
    #pragma unroll
    for (int j = 0; j < 8; ++j) v[j] = w_lds[klbase + j][o];
    *(f16x8*)(wsB + c * 4096 + t * 8) = v;
  }
}

// ---- main fused kernel: R7 structure, ZERO in-loop LDS reads ----
// 512 blocks x 256 threads (4 waves), 2 blocks/CU. Waves K-split 65 chunks
// (wave w: c = w + 4i, i = 0..15; wave 0 also bias c = 64). Triple-buffered
// register B stream. h values live in REGISTERS (hreg[4][2], extracted at
// compile-time indices) -- loaded once from wave-major LDS layout h_t.
__global__ __launch_bounds__(256) void main_kernel(
    const float* __restrict__ x, const float* __restrict__ gridp,
    const float* __restrict__ W1, const float* __restrict__ b1,
    const _Float16* __restrict__ wsB, float* __restrict__ out) {

  __shared__ _Float16 h_t[4][ROWS][16];        // 8192 B: h_t[w][row][i] = h[row][w+4i]
  __shared__ float part[4][ROWS * P_STRIDE];   // 69632 B; total 77824 -> 2/CU
  _Float16* x_lds = (_Float16*)&part[0][0];    // [64][X_STRIDE]; dead before part

  const int tid  = threadIdx.x;
  const int lane = tid & 63;
  const int wave = tid >> 6;
  const int rowblk = blockIdx.x * ROWS;

  // phase 0: issue coalesced x-tile load (16 consecutive f32 per thread)
  const float* xsrc = x + rowblk * 64 + tid * 16;
  f32x4 xr0 = *(const f32x4*)(xsrc);
  f32x4 xr1 = *(const f32x4*)(xsrc + 4);
  f32x4 xr2 = *(const f32x4*)(xsrc + 8);
  f32x4 xr3 = *(const f32x4*)(xsrc + 12);

  // phase 1: h. Thread (row = tid>>2, w4 = tid&3) computes the k-set of wave
  // w4: k = w4 + 4q, q = 0..15 -> h_t[w4][row][q]. Two b128 writes, no scatter.
  {
    int row = tid >> 2;
    int w4  = tid & 3;
    int r = rowblk + row;
    float g0 = gridp[r * 3 + 0], g1 = gridp[r * 3 + 1], g2 = gridp[r * 3 + 2];
    f16x8 h0, h1;
    #pragma unroll
    for (int q = 0; q < 16; ++q) {
      int k = w4 + 4 * q;
      float v = g0 * W1[k] + g1 * W1[64 + k] + g2 * W1[128 + k] + b1[k];
      float h = 0.5f * v * (1.0f + erff(v * 0.7071067811865476f));
      if (q < 8) h0[q] = (_Float16)h; else h1[q - 8] = (_Float16)h;
    }
    *(f16x8*)(&h_t[w4][row][0]) = h0;
    *(f16x8*)(&h_t[w4][row][8]) = h1;
  }

  // phase 2: x -> f16 -> LDS (coalesced-in, b128 LDS writes)
  {
    int row = tid >> 2, o = (tid & 3) * 16;
    f16x8 v0, v1;
    #pragma unroll
    for (int j = 0; j < 4; ++j) {
      v0[j]     = (_Float16)xr0[j];
      v0[4 + j] = (_Float16)xr1[j];
      v1[j]     = (_Float16)xr2[j];
      v1[4 + j] = (_Float16)xr3[j];
    }
    *(f16x8*)(&x_lds[row * X_STRIDE + o])     = v0;
    *(f16x8*)(&x_lds[row * X_STRIDE + o + 8]) = v1;
  }
  __syncthreads();

  const int mrow = lane & 15;        // A row within 16-tile / D col
  const int kgrp = lane >> 4;        // 0..3
  const _Float16* bp = wsB + lane * 8;

  auto LOADB = [&](f16x8* b, int c) {
    #pragma unroll
    for (int q = 0; q < 8; ++q)
      b[q] = *(const f16x8*)(bp + (c * 8 + q) * 512);
  };

  // issue first B batches before LDS reads (overlap global latency)
  f16x8 bA[8], bB[8], bC[8];
  LOADB(bA, wave);
  LOADB(bB, wave + 4);
  LOADB(bC, wave + 8);

  // h rows -> registers: hreg[m][half] covers chunk positions 0..15
  f16x8 hreg[4][2];
  #pragma unroll
  for (int m = 0; m < 4; ++m) {
    hreg[m][0] = *(const f16x8*)(&h_t[wave][m * 16 + mrow][0]);
    hreg[m][1] = *(const f16x8*)(&h_t[wave][m * 16 + mrow][8]);
  }

  // x fragments from LDS
  f16x8 xf[4][2];
  #pragma unroll
  for (int m = 0; m < 4; ++m)
    #pragma unroll
    for (int s = 0; s < 2; ++s)
      xf[m][s] = *(const f16x8*)(&x_lds[(m * 16 + mrow) * X_STRIDE + s * 32 + kgrp * 8]);

  f32x4 acc[4][4];
  #pragma unroll
  for (int m = 0; m < 4; ++m)
    #pragma unroll
    for (int n = 0; n < 4; ++n)
      acc[m][n] = (f32x4){0.f, 0.f, 0.f, 0.f};

  // COMPUTE for chunk position p (STATIC after unroll): h from registers.
  auto COMPUTE = [&](const f16x8* b, int p) {
    #pragma unroll
    for (int m = 0; m < 4; ++m) {
      _Float16 hh = hreg[m][p >> 3][p & 7];   // compile-time extraction
      f16x8 hs = {hh, hh, hh, hh, hh, hh, hh, hh};
      f16x8 a0 = xf[m][0] * hs;
      f16x8 a1 = xf[m][1] * hs;
      #pragma unroll
      for (int n = 0; n < 4; ++n) {
        acc[m][n] = __builtin_amdgcn_mfma_f32_16x16x32_f16(a0, b[n],     acc[m][n], 0, 0, 0);
        acc[m][n] = __builtin_amdgcn_mfma_f32_16x16x32_f16(a1, b[4 + n], acc[m][n], 0, 0, 0);
      }
    }
  };
  auto COMPUTE_BIAS = [&](const f16x8* b) {   // h == 1: A-frag = xf directly
    #pragma unroll
    for (int m = 0; m < 4; ++m)
      #pragma unroll
      for (int n = 0; n < 4; ++n) {
        acc[m][n] = __builtin_amdgcn_mfma_f32_16x16x32_f16(xf[m][0], b[n],     acc[m][n], 0, 0, 0);
        acc[m][n] = __builtin_amdgcn_mfma_f32_16x16x32_f16(xf[m][1], b[4 + n], acc[m][n], 0, 0, 0);
      }
  };

  // K-loop: positions p = 0..15 (c = wave + 4p), 3-buffer rotation, static.
  #pragma unroll
  for (int g = 0; g < 5; ++g) {
    COMPUTE(bA, 3 * g);
    if (3 * g + 3 < 16) LOADB(bA, wave + 4 * (3 * g + 3));
    COMPUTE(bB, 3 * g + 1);
    if (3 * g + 4 < 16) LOADB(bB, wave + 4 * (3 * g + 4));
    else if (wave == 0) LOADB(bB, 64);       // bias-chunk B, issued early
    COMPUTE(bC, 3 * g + 2);
    if (3 * g + 5 < 16) LOADB(bC, wave + 4 * (3 * g + 5));
  }
  COMPUTE(bA, 15);
  if (wave == 0) COMPUTE_BIAS(bB);

  __syncthreads();   // K-loop done everywhere; x_lds dead -> part writable

  // one-stage reduce: every wave writes its partial buffer...
  {
    float* pw = part[wave];
    #pragma unroll
    for (int m = 0; m < 4; ++m)
      #pragma unroll
      for (int n = 0; n < 4; ++n)
        #pragma unroll
        for (int r = 0; r < 4; ++r)
          pw[(m * 16 + kgrp * 4 + r) * P_STRIDE + n * 16 + mrow] = acc[m][n][r];
  }
  __syncthreads();

  // ...then all 256 threads sum 4 buffers and store (4 threads/row, 16 cols)
  {
    int row = tid >> 2;
    int cb  = (tid & 3) * 16;
    const float* p0 = part[0] + row * P_STRIDE + cb;
    float* op = out + (rowblk + row) * 64 + cb;
    #pragma unroll
    for (int j = 0; j < 4; ++j) {
      f32x4 s = *(const f32x4*)(p0 + j * 4);
      #pragma unroll
      for (int w = 1; w < 4; ++w)
        s += *(const f32x4*)(p0 + w * (ROWS * P_STRIDE) + j * 4);
      *(f32x4*)(op + j * 4) = s;
    }
  }
}

extern "C" void kernel_launch(void* const* d_in, const int* in_sizes, int n_in,
                              void* d_out, int out_size, void* d_ws, size_t ws_size,
                              hipStream_t stream) {
  const float* x    = (const float*)d_in[0];
  const float* grid = (const float*)d_in[1];
  const float* W1   = (const float*)d_in[2];
  const float* b1   = (const float*)d_in[3];
  const float* W2   = (const float*)d_in[4];
  const float* b2   = (const float*)d_in[5];
  float* out = (float*)d_out;
  _Float16* wsB = (_Float16*)d_ws;   // 65*4096*2 = 532480 bytes

  hipLaunchKernelGGL(prep_kernel, dim3(NCHUNK), dim3(256), 0, stream,
                     W2, b2, wsB);
  hipLaunchKernelGGL(main_kernel, dim3(N_PTS / ROWS), dim3(256), 0, stream,
                     x, grid, W1, b1, wsB, out);
}